// Round 7
// baseline (235.413 us; speedup 1.0000x reference)
//
#include <hip/hip_runtime.h>
#include <math.h>

#define EPSN 1e-5f

typedef __attribute__((ext_vector_type(8))) short bf16x8;
typedef __attribute__((ext_vector_type(4))) float f32x4;

__device__ __forceinline__ ushort f2bf(float f) {
  unsigned u = __float_as_uint(f);
  unsigned r = (u + 0x7fff + ((u >> 16) & 1)) >> 16;
  return (ushort)r;
}
__device__ __forceinline__ float bf2f(ushort h) {
  return __uint_as_float(((unsigned)h) << 16);
}

// ---------------- block-wide reductions (blockDim.x == 256, 4 waves) --------
__device__ __forceinline__ void breduce2(float& a, float& b, float* lds) {
#pragma unroll
  for (int o = 32; o > 0; o >>= 1) {
    a += __shfl_down(a, o);
    b += __shfl_down(b, o);
  }
  int lane = threadIdx.x & 63, wid = threadIdx.x >> 6;
  __syncthreads();
  if (lane == 0) { lds[wid] = a; lds[4 + wid] = b; }
  __syncthreads();
  a = lds[0] + lds[1] + lds[2] + lds[3];
  b = lds[4] + lds[5] + lds[6] + lds[7];
}

__device__ __forceinline__ float breduce_sum(float v, float* lds) {
#pragma unroll
  for (int o = 32; o > 0; o >>= 1) v += __shfl_down(v, o);
  int lane = threadIdx.x & 63, wid = threadIdx.x >> 6;
  __syncthreads();
  if (lane == 0) lds[wid] = v;
  __syncthreads();
  return lds[0] + lds[1] + lds[2] + lds[3];
}

__device__ __forceinline__ float breduce_max(float v, float* lds) {
#pragma unroll
  for (int o = 32; o > 0; o >>= 1) v = fmaxf(v, __shfl_down(v, o));
  int lane = threadIdx.x & 63, wid = threadIdx.x >> 6;
  __syncthreads();
  if (lane == 0) lds[wid] = v;
  __syncthreads();
  return fmaxf(fmaxf(lds[0], lds[1]), fmaxf(lds[2], lds[3]));
}

// ---------------- pre: bf16 converts + memsets + SK weight packing ----------
__global__ void pre_kernel(const float* __restrict__ gus,
                           const float* __restrict__ wdown,
                           const float* __restrict__ wfuse,
                           const float* __restrict__ w3,
                           const float* __restrict__ w5,
                           const float* __restrict__ w7,
                           ushort* __restrict__ gus_bf,
                           ushort* __restrict__ wdown_bf,
                           ushort* __restrict__ wfuse_bf,
                           ushort* __restrict__ resd,
                           ushort* __restrict__ Apk_g,
                           ushort* __restrict__ Acomb,
                           float* __restrict__ diagsum) {
  int bid = blockIdx.x, tid = threadIdx.x;
  if (bid < 2048) {
    int i = bid * 1024 + tid * 4;
    if (i < 1048576) {
      // gus: permute columns n -> packed r while converting to bf16
      float4 v = *(const float4*)&gus[i];
      int m = i >> 10, n = i & 1023;
      int y = n >> 5, x = n & 31;            // x % 4 == 0
      int idxb = ((y >> 1) << 4) + (x >> 1);
      int py = y & 1;
      ushort2 e0 = {f2bf(v.x), f2bf(v.z)};
      ushort2 e1 = {f2bf(v.y), f2bf(v.w)};
      *(ushort2*)&gus_bf[(size_t)m * 1024 + (py * 2 + 0) * 256 + idxb] = e0;
      *(ushort2*)&gus_bf[(size_t)m * 1024 + (py * 2 + 1) * 256 + idxb] = e1;
    } else {
      const float* src; ushort* dst; int off;
      if (i < 1572864) { src = wdown; dst = wdown_bf; off = i - 1048576; }
      else { src = wfuse; dst = wfuse_bf; off = i - 1572864; }
      float4 v = *(const float4*)&src[off];
      ushort4 o = {f2bf(v.x), f2bf(v.y), f2bf(v.z), f2bf(v.w)};
      *(ushort4*)&dst[off] = o;
    }
  } else if (bid < 2304) {
    int t8 = (bid - 2048) * 256 + tid;
    uint4 z = {0u, 0u, 0u, 0u};
#pragma unroll
    for (int k = 0; k < 4; ++k) *(uint4*)&resd[(size_t)(t8 + k * 65536) * 8] = z;
  } else if (bid < 5056) {
    int i2 = (bid - 2304) * 256 + tid;  // 0..704511
    int g = i2 / 22016;
    int r = i2 - g * 22016;
    int p = r >> 9;
    int r5 = r & 511;
    int quad = r5 >> 7, m16 = (r5 >> 3) & 15, j = r & 7;
    int k = quad * 8 + j, tp = k >> 4, ic = k & 15;
    float val = 0.f;
    if (p < 25) {
      int t = 2 * p + tp;
      if (t < 49) val = w7[(size_t)(g * 16 + m16) * 784 + ic * 49 + t];
    } else if (p < 38) {
      int t = 2 * (p - 25) + tp;
      if (t < 25) val = w5[(size_t)(g * 16 + m16) * 400 + ic * 25 + t];
    } else {
      int t = 2 * (p - 38) + tp;
      if (t < 9) val = w3[(size_t)(g * 16 + m16) * 144 + ic * 9 + t];
    }
    Apk_g[i2] = f2bf(val);
  } else if (bid < 5568) {
    // zero Acomb (invalid border taps must read as 0)
    int j = (bid - 5056) * 256 + tid;  // < 131072
    uint4 z = {0u, 0u, 0u, 0u};
    ((uint4*)Acomb)[j] = z;
  } else {
    diagsum[tid] = 0.f;
  }
}

// ---------------- fused SKConv + InstanceNorm + ReLU + branch-mean ----------
// One block per group (grid 32): whole 32x32 image x 16 channels is
// block-local, so per-channel norm stats need no second kernel. A panel is
// block-copied from pre-packed global Apk_g (coalesced, no re-gather).
__global__ __launch_bounds__(256) void sk_fused(const float* __restrict__ x,
                                                const ushort* __restrict__ Apk_g,
                                                ushort* __restrict__ feasH,
                                                float* __restrict__ bmean) {
  __shared__ ushort apk[22016];        // 44 KB packed A panel
  __shared__ ushort xg[38 * 38 * 24];  // 69.3 KB: rows/cols -3..34, ic pad 24
  __shared__ float red[4][4][8];       // [wave][quad][r | 4+r]
  int g = blockIdx.x, tid = threadIdx.x;
  for (int i = tid; i < 17328; i += 256) ((uint*)xg)[i] = 0u;
  {
    const uint4* src = (const uint4*)(Apk_g + (size_t)g * 22016);
    for (int i = tid; i < 2752; i += 256) ((uint4*)apk)[i] = src[i];
  }
  __syncthreads();
  for (int i = tid; i < 16384; i += 256) {
    int ic = i >> 10, pos = i & 1023;
    int y = pos >> 5, xc = pos & 31;
    xg[((y + 3) * 38 + xc + 3) * 24 + ic] =
        f2bf(x[(size_t)(g * 16 + ic) * 1024 + pos]);
  }
  __syncthreads();
  int wv = tid >> 6, lane = tid & 63, quad = lane >> 4, m16 = lane & 15;
  int qh = (quad & 1) * 8, tp = quad >> 1;
  int lanebase = m16 * 8;
  // p-invariant xg offsets for the 16 (slice, tile) combos of this thread
  int off16[16];
#pragma unroll
  for (int s = 0; s < 8; ++s)
#pragma unroll
    for (int ti = 0; ti < 2; ++ti) {
      int T = wv + ti * 4, tl = T >> 1, x0c = (T & 1) * 16;
      off16[s * 2 + ti] = ((s * 4 + tl) * 38 + x0c + m16) * 24 + qh;
    }

#define SK_BRANCH(NP, POFF, KS, TMAX, SHIFT, BR)                               \
  {                                                                            \
    f32x4 acc[16] = {};                                                        \
    for (int p = 0; p < NP; ++p) {                                             \
      bf16x8 af = *(const bf16x8*)&apk[((p + POFF) * 4 + quad) * 128 + lanebase]; \
      int t = 2 * p + tp;                                                      \
      if (t > TMAX) t = TMAX;                                                  \
      int ky = t / KS, kx = t - ky * KS;                                       \
      int base = (ky * 38 + kx + SHIFT * 39) * 24;                             \
      _Pragma("unroll")                                                        \
      for (int u = 0; u < 16; ++u) {                                           \
        bf16x8 bf = *(const bf16x8*)&xg[off16[u] + base];                      \
        acc[u] = __builtin_amdgcn_mfma_f32_16x16x32_bf16(af, bf, acc[u], 0, 0, 0); \
      }                                                                        \
    }                                                                          \
    /* per-channel stats over 1024 positions (64-thread quad-groups) */        \
    float s4[4] = {0.f, 0.f, 0.f, 0.f}, ss4[4] = {0.f, 0.f, 0.f, 0.f};         \
    _Pragma("unroll")                                                          \
    for (int u = 0; u < 16; ++u)                                               \
      _Pragma("unroll")                                                        \
      for (int r = 0; r < 4; ++r) {                                            \
        float v = acc[u][r];                                                   \
        s4[r] += v;                                                            \
        ss4[r] += v * v;                                                       \
      }                                                                        \
    _Pragma("unroll")                                                          \
    for (int o = 8; o > 0; o >>= 1)                                            \
      _Pragma("unroll")                                                        \
      for (int r = 0; r < 4; ++r) {                                            \
        s4[r] += __shfl_xor(s4[r], o);                                         \
        ss4[r] += __shfl_xor(ss4[r], o);                                       \
      }                                                                        \
    if (m16 == 0)                                                              \
      _Pragma("unroll")                                                        \
      for (int r = 0; r < 4; ++r) {                                            \
        red[wv][quad][r] = s4[r];                                              \
        red[wv][quad][4 + r] = ss4[r];                                         \
      }                                                                        \
    __syncthreads();                                                           \
    float mean[4], inv[4];                                                     \
    _Pragma("unroll")                                                          \
    for (int r = 0; r < 4; ++r) {                                              \
      float S = red[0][quad][r] + red[1][quad][r] + red[2][quad][r] +          \
                red[3][quad][r];                                               \
      float SS = red[0][quad][4 + r] + red[1][quad][4 + r] +                   \
                 red[2][quad][4 + r] + red[3][quad][4 + r];                    \
      mean[r] = S * (1.f / 1024.f);                                            \
      inv[r] = rsqrtf(SS * (1.f / 1024.f) - mean[r] * mean[r] + EPSN);         \
    }                                                                          \
    float rs[4] = {0.f, 0.f, 0.f, 0.f};                                        \
    _Pragma("unroll")                                                          \
    for (int u = 0; u < 16; ++u) {                                             \
      int T = wv + (u & 1) * 4, tl = T >> 1, x0c = (T & 1) * 16;               \
      int pos = ((u >> 1) * 4 + tl) * 32 + x0c + m16;                          \
      _Pragma("unroll")                                                        \
      for (int r = 0; r < 4; ++r) {                                            \
        float tv = (acc[u][r] - mean[r]) * inv[r];                             \
        tv = tv > 0.f ? tv : 0.f;                                              \
        feasH[(size_t)(BR * 512 + g * 16 + quad * 4 + r) * 1024 + pos] =       \
            f2bf(tv);                                                          \
        rs[r] += tv;                                                           \
      }                                                                        \
    }                                                                          \
    _Pragma("unroll")                                                          \
    for (int o = 8; o > 0; o >>= 1)                                            \
      _Pragma("unroll")                                                        \
      for (int r = 0; r < 4; ++r) rs[r] += __shfl_xor(rs[r], o);               \
    __syncthreads();                                                           \
    if (m16 == 0)                                                              \
      _Pragma("unroll")                                                        \
      for (int r = 0; r < 4; ++r) red[wv][quad][r] = rs[r];                    \
    __syncthreads();                                                           \
    if (wv == 0 && m16 == 0)                                                   \
      _Pragma("unroll")                                                        \
      for (int r = 0; r < 4; ++r)                                              \
        bmean[BR * 512 + g * 16 + quad * 4 + r] =                              \
            (red[0][quad][r] + red[1][quad][r] + red[2][quad][r] +             \
             red[3][quad][r]) * (1.f / 1024.f);                                \
    __syncthreads();                                                           \
  }

  SK_BRANCH(25, 0, 7, 48, 0, 2)   // k7 -> branch 2
  SK_BRANCH(13, 25, 5, 24, 1, 1)  // k5 -> branch 1
  SK_BRANCH(5, 38, 3, 8, 2, 0)    // k3 -> branch 0
#undef SK_BRANCH
}

// ---------------- blend + FC-attention; reads bf16 feas ---------------------
__global__ __launch_bounds__(256) void blend_fc(
    const ushort* __restrict__ feasH, const float* __restrict__ bmean,
    const float* __restrict__ wfc, const float* __restrict__ bfc,
    const float* __restrict__ w0, const float* __restrict__ b0,
    const float* __restrict__ w1, const float* __restrict__ b1,
    const float* __restrict__ w2, const float* __restrict__ b2,
    float* __restrict__ res, ushort* __restrict__ Zt2,
    ushort* __restrict__ resd) {
  __shared__ float sfea[512];
  __shared__ float zpart[8][32];
  __shared__ float zz[32];
  __shared__ float lv[3][32];
  __shared__ float attb[3][32];
  __shared__ float tile[32][33];
  int tid = threadIdx.x;
  int pb = blockIdx.x * 32, cb = blockIdx.y * 32;
  for (int c = tid; c < 512; c += 256)
    sfea[c] = bmean[c] + bmean[512 + c] + bmean[1024 + c];
  __syncthreads();
  {
    int j = tid & 31, seg = tid >> 5;
    float p = 0.f;
    for (int c = seg * 64; c < seg * 64 + 64; ++c) p += sfea[c] * wfc[j * 512 + c];
    zpart[seg][j] = p;
  }
  __syncthreads();
  if (tid < 32) {
    float d = bfc[tid];
#pragma unroll
    for (int s = 0; s < 8; ++s) d += zpart[s][tid];
    zz[tid] = d;
  }
  __syncthreads();
  if (tid < 96) {
    int m = tid >> 5, cl = tid & 31;
    const float* wm = (m == 0) ? w0 : (m == 1) ? w1 : w2;
    const float* bm = (m == 0) ? b0 : (m == 1) ? b1 : b2;
    float l = bm[cb + cl];
#pragma unroll
    for (int j = 0; j < 32; ++j) l += zz[j] * wm[(cb + cl) * 32 + j];
    lv[m][cl] = l;
  }
  __syncthreads();
  if (tid < 32) {
    float l0 = lv[0][tid], l1 = lv[1][tid], l2 = lv[2][tid];
    float mx = fmaxf(l0, fmaxf(l1, l2));
    float e0 = expf(l0 - mx), e1 = expf(l1 - mx), e2 = expf(l2 - mx);
    float inv = 1.f / (e0 + e1 + e2);
    attb[0][tid] = e0 * inv; attb[1][tid] = e1 * inv; attb[2][tid] = e2 * inv;
  }
  __syncthreads();
  int tx = tid & 31, ty = tid >> 5;
  int pos = pb + tx;
  int yy = pos >> 5, xx = pos & 31;
  int ki0 = (yy + 1) & 1, pi0 = (yy + 1 - ki0) >> 1;
  int kj0 = (xx + 1) & 1, pj0 = (xx + 1 - kj0) >> 1;
#pragma unroll
  for (int r = 0; r < 4; ++r) {
    int cl = ty + r * 8;
    int c = cb + cl;
    float v = bf2f(feasH[(size_t)c * 1024 + pos]) * attb[0][cl] +
              bf2f(feasH[(size_t)(512 + c) * 1024 + pos]) * attb[1][cl] +
              bf2f(feasH[(size_t)(1024 + c) * 1024 + pos]) * attb[2][cl];
    res[c * 1024 + pos] = v;
    tile[cl][tx] = v;
    ushort bv16 = f2bf(v);
#pragma unroll
    for (int ai = 0; ai < 2; ++ai) {
      int ki = ki0 + 2 * ai, pi = pi0 - ai;
      if ((unsigned)pi >= 16u) continue;
#pragma unroll
      for (int aj = 0; aj < 2; ++aj) {
        int kj = kj0 + 2 * aj, pj = pj0 - aj;
        if ((unsigned)pj >= 16u) continue;
        resd[((size_t)(ki * 4 + kj) << 17) + (size_t)c * 256 + pi * 16 + pj] = bv16;
      }
    }
  }
  __syncthreads();
#pragma unroll
  for (int r = 0; r < 4; ++r) {
    int pl = ty + r * 8;
    Zt2[(size_t)(pb + pl) * 1024 + 512 + cb + tx] = f2bf(tile[tx][pl]);
  }
}

// ---------------- Gram split-K partials, SYMMETRIC (upper pairs only) -------
__global__ __launch_bounds__(256) void gram_part2(const float* __restrict__ res,
                                                  float* __restrict__ Apart,
                                                  float* __restrict__ diagsum) {
  __shared__ float ch[4][324];
  const int PBT[10] = {0, 0, 0, 0, 1, 1, 1, 2, 2, 3};
  const int QBT[10] = {0, 1, 2, 3, 1, 2, 3, 2, 3, 3};
  int tid = threadIdx.x;
  int pid = blockIdx.x;
  int pb = PBT[pid] * 64, qb = QBT[pid] * 64;
  int kc = blockIdx.z;
  int tx = tid & 15, ty = tid >> 4;
  for (int i = tid; i < 4 * 324; i += 256) ((float*)ch)[i] = 0.f;
  int pi = (pb + ty * 4) >> 4, pj = (pb + ty * 4) & 15;
  int qi = (qb + tx * 4) >> 4, qj = (qb + tx * 4) & 15;
  int lane = tid & 63, wv = tid >> 6;
  int sr = lane >> 2, sc = (lane & 3) * 4;
  float acc[4][4] = {};
  for (int c0 = kc * 16; c0 < kc * 16 + 16; c0 += 4) {
    __syncthreads();
    {
      const float* src = res + (size_t)(c0 + wv) * 1024 + (2 * sr) * 32 + 2 * sc;
      float4 r0a = *(const float4*)src;
      float4 r0b = *(const float4*)(src + 4);
      float4 r1a = *(const float4*)(src + 32);
      float4 r1b = *(const float4*)(src + 36);
      float* dst = &ch[wv][(sr + 1) * 18 + sc + 1];
      dst[0] = 0.25f * (r0a.x + r0a.y + r1a.x + r1a.y);
      dst[1] = 0.25f * (r0a.z + r0a.w + r1a.z + r1a.w);
      dst[2] = 0.25f * (r0b.x + r0b.y + r1b.x + r1b.y);
      dst[3] = 0.25f * (r0b.z + r0b.w + r1b.z + r1b.w);
    }
    __syncthreads();
#pragma unroll
    for (int cc = 0; cc < 4; ++cc) {
      float ps[3][6], qs[3][6];
#pragma unroll
      for (int u = 0; u < 3; ++u) {
        const float* pr = &ch[cc][(pi + u) * 18 + pj];
        const float* qr = &ch[cc][(qi + u) * 18 + qj];
#pragma unroll
        for (int t = 0; t < 6; ++t) { ps[u][t] = pr[t]; qs[u][t] = qr[t]; }
      }
#pragma unroll
      for (int u = 0; u < 3; ++u)
#pragma unroll
        for (int v = 0; v < 3; ++v)
#pragma unroll
          for (int i = 0; i < 4; ++i)
#pragma unroll
            for (int j = 0; j < 4; ++j)
              acc[i][j] += ps[u][v + i] * qs[u][v + j];
    }
  }
#pragma unroll
  for (int i = 0; i < 4; ++i) {
    float4 o4 = {acc[i][0], acc[i][1], acc[i][2], acc[i][3]};
    *(float4*)&Apart[(size_t)kc * 65536 + (pb + ty * 4 + i) * 256 + qb + tx * 4] = o4;
  }
  if (pb != qb) {
#pragma unroll
    for (int j = 0; j < 4; ++j) {
      float4 o4 = {acc[0][j], acc[1][j], acc[2][j], acc[3][j]};
      *(float4*)&Apart[(size_t)kc * 65536 + (qb + tx * 4 + j) * 256 + pb + ty * 4] = o4;
    }
  } else if (tx == ty) {
#pragma unroll
    for (int i = 0; i < 4; ++i) atomicAdd(&diagsum[pb + tx * 4 + i], acc[i][i]);
  }
}

// ---------------- softmax + diag norm -> Acomb (class-packed rows) ----------
__global__ __launch_bounds__(256) void attn_soft4(const float* __restrict__ Apart,
                                                  const float* __restrict__ diagsum,
                                                  ushort* __restrict__ Acomb) {
  __shared__ float red[8];
  int q = blockIdx.x, t = threadIdx.x;
  float d = diagsum[t];
  float s = 0.f;
#pragma unroll
  for (int k = 0; k < 32; ++k) s += Apart[(size_t)k * 65536 + q * 256 + t];
  float invn = 10.f / fmaxf(sqrtf(fmaxf(d, 0.f)), 1e-4f);
  float v = s * invn;
  float mx = breduce_max(v, red);
  float e = expf(v - mx);
  float sm = breduce_sum(e, red);
  ushort val = f2bf(e / sm);
  int qi = q >> 4, qj = q & 15;
#pragma unroll
  for (int ki = 0; ki < 4; ++ki) {
    int y = 2 * qi + ki - 1;
    if ((unsigned)y >= 32u) continue;
#pragma unroll
    for (int kj = 0; kj < 4; ++kj) {
      int x = 2 * qj + kj - 1;
      if ((unsigned)x >= 32u) continue;
      int cls = (y & 1) * 2 + (x & 1);
      int idx = ((y >> 1) << 4) + (x >> 1);
      int seg = ((ki >> 1) << 1) + (kj >> 1);
      Acomb[(size_t)(cls * 256 + idx) * 1024 + seg * 256 + t] = val;
    }
  }
}

// ---------------- fused tconv+tcomb: K=4x256 GEMM over class-shared taps ----
__global__ __launch_bounds__(256) void tconv2(const ushort* __restrict__ Acomb,
                                              const ushort* __restrict__ resd,
                                              float* __restrict__ orlt,
                                              float* __restrict__ sigt,
                                              ushort* __restrict__ orlT) {
  __shared__ float tl[64][33];
  int tid = threadIdx.x;
  int wv = tid >> 6, lane = tid & 63, quad = lane >> 4, m16 = lane & 15;
  int nb = blockIdx.x * 32;   // channel tile
  int mb = blockIdx.y * 64;   // packed-row tile
  int cls = blockIdx.y >> 2;
  int py = cls >> 1, px = cls & 1;
  int row0 = mb + wv * 16 + m16;
  const ushort* Ap = Acomb + (size_t)row0 * 1024 + quad * 8;
  f32x4 ac0 = {0.f, 0.f, 0.f, 0.f}, ac1 = ac0;
#pragma unroll
  for (int sg = 0; sg < 4; ++sg) {
    int ki = 2 * (sg >> 1) + 1 - py;
    int kj = 2 * (sg & 1) + 1 - px;
    const ushort* Bp =
        resd + ((size_t)(ki * 4 + kj) << 17) + (size_t)(nb + m16) * 256 + quad * 8;
    const ushort* As = Ap + sg * 256;
#pragma unroll 4
    for (int k0 = 0; k0 < 256; k0 += 32) {
      bf16x8 af = *(const bf16x8*)(As + k0);
      bf16x8 b0 = *(const bf16x8*)(Bp + k0);
      bf16x8 b1 = *(const bf16x8*)(Bp + 16 * 256 + k0);
      ac0 = __builtin_amdgcn_mfma_f32_16x16x32_bf16(af, b0, ac0, 0, 0, 0);
      ac1 = __builtin_amdgcn_mfma_f32_16x16x32_bf16(af, b1, ac1, 0, 0, 0);
    }
  }
  int rloc0 = wv * 16 + quad * 4;
  f32x4 accs[2] = {ac0, ac1};
#pragma unroll
  for (int nt = 0; nt < 2; ++nt) {
    int c = nb + nt * 16 + m16;
#pragma unroll
    for (int r = 0; r < 4; ++r) {
      int rl = rloc0 + r;
      int idx = (mb + rl) & 255;
      int y = ((idx >> 4) << 1) + py;
      int x = ((idx & 15) << 1) + px;
      int n = y * 32 + x;
      float v = accs[nt][r] * 0.25f;
      orlt[n * 512 + c] = v;
      sigt[n * 512 + c] = 1.f / (1.f + expf(-v));
      tl[rl][nt * 16 + m16] = v;
    }
  }
  __syncthreads();
  int r_l = tid & 63;
#pragma unroll
  for (int k = 0; k < 8; ++k) {
    int c_l = (tid >> 6) + k * 4;
    orlT[(size_t)(nb + c_l) * 1024 + mb + r_l] = f2bf(tl[r_l][c_l]);
  }
}

// ---------------- merged: gus GEMM (blocks 0..127) + CSA (128..1151) --------
__global__ __launch_bounds__(256) void gus_csa(
    const ushort* __restrict__ gus_bf, const ushort* __restrict__ orlT,
    const float* __restrict__ sigt, const float* __restrict__ orlt,
    ushort* __restrict__ Zt) {
  __shared__ float red9[4][9];
  __shared__ float a9s[9];
  int tid = threadIdx.x;
  if (blockIdx.x < 128) {
    const int K = 1024;
    int wv = tid >> 6, lane = tid & 63;
    int quad = lane >> 4, m16 = lane & 15;
    int nb = (blockIdx.x & 7) * 64, mb = (blockIdx.x >> 3) * 64;
    const ushort* Ap = gus_bf + (size_t)(mb + wv * 16 + m16) * K + quad * 8;
    const ushort* Bp = orlT + (size_t)(nb + m16) * K + quad * 8;
    f32x4 ac0 = {0.f, 0.f, 0.f, 0.f}, ac1 = ac0, ac2 = ac0, ac3 = ac0;
#pragma unroll 4
    for (int k0 = 0; k0 < K; k0 += 32) {
      bf16x8 af = *(const bf16x8*)(Ap + k0);
      bf16x8 b0 = *(const bf16x8*)(Bp + k0);
      bf16x8 b1 = *(const bf16x8*)(Bp + (size_t)16 * K + k0);
      bf16x8 b2 = *(const bf16x8*)(Bp + (size_t)32 * K + k0);
      bf16x8 b3 = *(const bf16x8*)(Bp + (size_t)48 * K + k0);
      ac0 = __builtin_amdgcn_mfma_f32_16x16x32_bf16(af, b0, ac0, 0, 0, 0);
      ac1 = __builtin_amdgcn_mfma_f32_16x16x32_bf16(af, b1, ac1, 0, 0, 0);
      ac2 = __builtin_amdgcn_mfma_f32_16x16x32_bf16(af, b2, ac2, 0, 0, 0);
      ac3 = __builtin_amdgcn_mfma_f32_16x16x32_bf16(af, b3, ac3, 0, 0, 0);
    }
    int row = mb + wv * 16 + quad * 4;
    f32x4 accs[4] = {ac0, ac1, ac2, ac3};
#pragma unroll
    for (int nt = 0; nt < 4; ++nt) {
      int c = nb + nt * 16 + m16;
#pragma unroll
      for (int r = 0; r < 4; ++r) {
        int p = row + r;
        int pos = ((p & 1) << 9) + c;
        int kk = p >> 1;
        Zt[(size_t)pos * 1024 + kk] = f2bf(accs[nt][r]);
      }
    }
    return;
  }
  int n = blockIdx.x - 128;
  int ny = n >> 5, nx = n & 31;
  int c2 = tid * 2;
  int lane = tid & 63, wid = tid >> 6;
  float2 ctr = *(const float2*)&sigt[n * 512 + c2];
  float part[9];
#pragma unroll
  for (int u = 0; u < 3; ++u) {
    int yy = ny + u - 1;
#pragma unroll
    for (int v = 0; v < 3; ++v) {
      int xx = nx + v - 1;
      float2 nb2 = {0.f, 0.f};
      if ((unsigned)yy < 32u && (unsigned)xx < 32u)
        nb2 = *(const float2*)&sigt[(yy * 32 + xx) * 512 + c2];
      part[u * 3 + v] = ctr.x * nb2.x + ctr.y * nb2.y;
    }
  }
#pragma unroll
  for (int t = 0; t < 9; ++t)
#pragma unroll
    for (int o = 32; o > 0; o >>= 1) part[t] += __shfl_down(part[t], o);
  if (lane == 0)
#pragma unroll
    for (int t = 0; t < 9; ++t) red9[wid][t] = part[t];
  __syncthreads();
  if (tid == 0) {
    float a[9];
#pragma unroll
    for (int t = 0; t < 9; ++t)
      a[t] = (red9[0][t] + red9[1][t] + red9[2][t] + red9[3][t]) * (1.f / 512.f);
    float mx = a[0];
#pragma unroll
    for (int t = 1; t < 9; ++t) mx = fmaxf(mx, a[t]);
    float sum = 0.f;
#pragma unroll
    for (int t = 0; t < 9; ++t) { a[t] = expf(a[t] - mx); sum += a[t]; }
    float inv = 1.f / sum;
#pragma unroll
    for (int t = 0; t < 9; ++t) a9s[t] = a[t] * inv;
  }
  __syncthreads();
  float2 acc = {0.f, 0.f};
#pragma unroll
  for (int u = 0; u < 3; ++u) {
    int yy = ny + u - 1;
#pragma unroll
    for (int v = 0; v < 3; ++v) {
      int xx = nx + v - 1;
      if ((unsigned)yy < 32u && (unsigned)xx < 32u) {
        float w = a9s[u * 3 + v];
        float2 ov = *(const float2*)&orlt[(yy * 32 + xx) * 512 + c2];
        acc.x += w * ov.x;
        acc.y += w * ov.y;
      }
    }
  }
  int kk = 512 + (n >> 1);
  int pos0 = ((n & 1) << 9) + c2;
  Zt[(size_t)pos0 * 1024 + kk] = f2bf(acc.x);
  Zt[(size_t)(pos0 + 1) * 1024 + kk] = f2bf(acc.y);
}

// ---------------- K-split bf16 MFMA GEMM: 2 halves -> 2 fp32 partials -------
__global__ __launch_bounds__(256) void mfma_gemm_ks(const ushort* __restrict__ A,
                                                    const ushort* __restrict__ Bt,
                                                    float* __restrict__ Cp,
                                                    int N) {
  const int KF = 1024;
  int tid = threadIdx.x;
  int wv = tid >> 6, lane = tid & 63;
  int quad = lane >> 4, m16 = lane & 15;
  int nb = blockIdx.x * 64, mb = blockIdx.y * 64;
  int kh = blockIdx.z;
  const ushort* Ap = A + (size_t)(mb + wv * 16 + m16) * KF + kh * 512 + quad * 8;
  const ushort* Bp = Bt + (size_t)(nb + m16) * KF + kh * 512 + quad * 8;
  f32x4 ac0 = {0.f, 0.f, 0.f, 0.f}, ac1 = ac0, ac2 = ac0, ac3 = ac0;
#pragma unroll 4
  for (int k0 = 0; k0 < 512; k0 += 32) {
    bf16x8 af = *(const bf16x8*)(Ap + k0);
    bf16x8 b0 = *(const bf16x8*)(Bp + k0);
    bf16x8 b1 = *(const bf16x8*)(Bp + (size_t)16 * KF + k0);
    bf16x8 b2 = *(const bf16x8*)(Bp + (size_t)32 * KF + k0);
    bf16x8 b3 = *(const bf16x8*)(Bp + (size_t)48 * KF + k0);
    ac0 = __builtin_amdgcn_mfma_f32_16x16x32_bf16(af, b0, ac0, 0, 0, 0);
    ac1 = __builtin_amdgcn_mfma_f32_16x16x32_bf16(af, b1, ac1, 0, 0, 0);
    ac2 = __builtin_amdgcn_mfma_f32_16x16x32_bf16(af, b2, ac2, 0, 0, 0);
    ac3 = __builtin_amdgcn_mfma_f32_16x16x32_bf16(af, b3, ac3, 0, 0, 0);
  }
  int row = mb + wv * 16 + quad * 4;
  float* C = Cp + (size_t)kh * 524288;
  f32x4 accs[4] = {ac0, ac1, ac2, ac3};
#pragma unroll
  for (int nt = 0; nt < 4; ++nt)
#pragma unroll
    for (int r = 0; r < 4; ++r)
      C[(size_t)(row + r) * N + nb + nt * 16 + m16] = accs[nt][r];
}

// ---------------- InstanceNorm + LeakyReLU (sum 2 partials) -> Zt2 bf16 -----
__global__ __launch_bounds__(256) void norm_down2(const float* __restrict__ ra,
                                                  ushort* __restrict__ Zt2) {
  __shared__ float red[8];
  int c = blockIdx.x, tid = threadIdx.x;
  float v[4];
  float s = 0.f, ss = 0.f;
#pragma unroll
  for (int r = 0; r < 4; ++r) {
    int i = c * 1024 + tid + r * 256;
    v[r] = ra[i] + ra[524288 + i];
    s += v[r];
    ss += v[r] * v[r];
  }
  breduce2(s, ss, red);
  float mean = s * (1.f / 1024.f);
  float var = ss * (1.f / 1024.f) - mean * mean;
  float inv = rsqrtf(var + EPSN);
#pragma unroll
  for (int r = 0; r < 4; ++r) {
    float t = (v[r] - mean) * inv;
    t = t >= 0.f ? t : 0.2f * t;
    Zt2[(size_t)(tid + r * 256) * 1024 + c] = f2bf(t);
  }
}

// ---------------- final InstanceNorm + LeakyReLU (sum 2 partials) -----------
__global__ __launch_bounds__(256) void norm_leaky2(const float* __restrict__ ra,
                                                   float* __restrict__ out) {
  __shared__ float red[8];
  int c = blockIdx.x, tid = threadIdx.x;
  float v[4];
  float s = 0.f, ss = 0.f;
#pragma unroll
  for (int r = 0; r < 4; ++r) {
    int i = c * 1024 + tid + r * 256;
    v[r] = ra[i] + ra[524288 + i];
    s += v[r];
    ss += v[r] * v[r];
  }
  breduce2(s, ss, red);
  float mean = s * (1.f / 1024.f);
  float var = ss * (1.f / 1024.f) - mean * mean;
  float inv = rsqrtf(var + EPSN);
#pragma unroll
  for (int r = 0; r < 4; ++r) {
    float t = (v[r] - mean) * inv;
    out[c * 1024 + tid + r * 256] = t >= 0.f ? t : 0.2f * t;
  }
}

// ---------------- host launch ------------------------------------------------
extern "C" void kernel_launch(void* const* d_in, const int* in_sizes, int n_in,
                              void* d_out, int out_size, void* d_ws, size_t ws_size,
                              hipStream_t stream) {
  const float* x = (const float*)d_in[0];
  const float* gus = (const float*)d_in[1];
  const float* w3 = (const float*)d_in[2];
  const float* w5 = (const float*)d_in[4];
  const float* w7 = (const float*)d_in[6];
  const float* wfc = (const float*)d_in[8];
  const float* bfc = (const float*)d_in[9];
  const float* w0 = (const float*)d_in[10];
  const float* b0 = (const float*)d_in[11];
  const float* w1 = (const float*)d_in[12];
  const float* b1 = (const float*)d_in[13];
  const float* w2 = (const float*)d_in[14];
  const float* b2 = (const float*)d_in[15];
  const float* wdown = (const float*)d_in[16];
  const float* wfuse = (const float*)d_in[17];

  float* ws = (float*)d_ws;
  ushort* feasH = (ushort*)ws;           // 1572864 ush (dead after blend)
  float* rawP = ws + 786432;             // 2x524288 fl partials / Acomb alias
  ushort* Acomb = (ushort*)rawP;
  float* bmean = ws + 1835008;           // 1536
  float* res = bmean + 1536;             // 524288
  float* Zt2f = res + 524288;            // 524288 fl
  ushort* Zt2 = (ushort*)Zt2f;
  float* T = Zt2f + 524288;              // 2097152 (Apart/Zt alias)
  float* Apart = T;
  ushort* Zt = (ushort*)T;
  float* orlt = T + 2097152;             // 524288
  float* sigt = orlt + 524288;           // 524288
  ushort* orlT = (ushort*)(sigt + 524288);        // 262144 fl
  ushort* gus_bf = (ushort*)(sigt + 819200);      // 524288 fl
  ushort* wdown_bf = (ushort*)(sigt + 1343488);   // 262144 fl
  ushort* wfuse_bf = (ushort*)(sigt + 1605632);   // 262144 fl
  ushort* resd = (ushort*)(sigt + 1867776);       // 1048576 fl
  ushort* Apk_g = (ushort*)(sigt + 2916352);      // 704512 ush
  float* diagsum = sigt + 3268608;                // 256 fl

  pre_kernel<<<5569, 256, 0, stream>>>(gus, wdown, wfuse, w3, w5, w7, gus_bf,
                                       wdown_bf, wfuse_bf, resd, Apk_g, Acomb,
                                       diagsum);
  sk_fused<<<32, 256, 0, stream>>>(x, Apk_g, feasH, bmean);
  blend_fc<<<dim3(32, 16), 256, 0, stream>>>(feasH, bmean, wfc, bfc, w0, b0, w1,
                                             b1, w2, b2, res, Zt2, resd);
  gram_part2<<<dim3(10, 1, 32), 256, 0, stream>>>(res, Apart, diagsum);
  attn_soft4<<<256, 256, 0, stream>>>(Apart, diagsum, Acomb);
  tconv2<<<dim3(16, 16), 256, 0, stream>>>(Acomb, resd, orlt, sigt, orlT);
  gus_csa<<<1152, 256, 0, stream>>>(gus_bf, orlT, sigt, orlt, Zt);
  mfma_gemm_ks<<<dim3(16, 8, 2), 256, 0, stream>>>(wdown_bf, Zt, rawP, 1024);
  norm_down2<<<512, 256, 0, stream>>>(rawP, Zt2);
  mfma_gemm_ks<<<dim3(16, 8, 2), 256, 0, stream>>>(wfuse_bf, Zt2, rawP, 1024);
  norm_leaky2<<<512, 256, 0, stream>>>(rawP, (float*)d_out);
}

// Round 8
// 216.904 us; speedup vs baseline: 1.0853x; 1.0853x over previous
//
#include <hip/hip_runtime.h>
#include <math.h>

#define EPSN 1e-5f

typedef __attribute__((ext_vector_type(8))) short bf16x8;
typedef __attribute__((ext_vector_type(4))) float f32x4;

__device__ __forceinline__ ushort f2bf(float f) {
  unsigned u = __float_as_uint(f);
  unsigned r = (u + 0x7fff + ((u >> 16) & 1)) >> 16;
  return (ushort)r;
}
__device__ __forceinline__ float bf2f(ushort h) {
  return __uint_as_float(((unsigned)h) << 16);
}

// ---------------- block-wide reductions (blockDim.x == 256, 4 waves) --------
__device__ __forceinline__ void breduce2(float& a, float& b, float* lds) {
#pragma unroll
  for (int o = 32; o > 0; o >>= 1) {
    a += __shfl_down(a, o);
    b += __shfl_down(b, o);
  }
  int lane = threadIdx.x & 63, wid = threadIdx.x >> 6;
  __syncthreads();
  if (lane == 0) { lds[wid] = a; lds[4 + wid] = b; }
  __syncthreads();
  a = lds[0] + lds[1] + lds[2] + lds[3];
  b = lds[4] + lds[5] + lds[6] + lds[7];
}

__device__ __forceinline__ float breduce_sum(float v, float* lds) {
#pragma unroll
  for (int o = 32; o > 0; o >>= 1) v += __shfl_down(v, o);
  int lane = threadIdx.x & 63, wid = threadIdx.x >> 6;
  __syncthreads();
  if (lane == 0) lds[wid] = v;
  __syncthreads();
  return lds[0] + lds[1] + lds[2] + lds[3];
}

__device__ __forceinline__ float breduce_max(float v, float* lds) {
#pragma unroll
  for (int o = 32; o > 0; o >>= 1) v = fmaxf(v, __shfl_down(v, o));
  int lane = threadIdx.x & 63, wid = threadIdx.x >> 6;
  __syncthreads();
  if (lane == 0) lds[wid] = v;
  __syncthreads();
  return fmaxf(fmaxf(lds[0], lds[1]), fmaxf(lds[2], lds[3]));
}

// ---------------- pre: bf16 converts + resd/Acomb/diag memset + SK packing --
// gus_bf is written COLUMN-PERMUTED into packed-r order:
//   r = cls*256 + (y>>1)*16 + (x>>1), cls = (y&1)*2 + (x&1)
// so that the gus GEMM's K axis matches orlT's packed-r layout.
__global__ void pre_kernel(const float* __restrict__ gus,
                           const float* __restrict__ wdown,
                           const float* __restrict__ wfuse,
                           const float* __restrict__ w3,
                           const float* __restrict__ w5,
                           const float* __restrict__ w7,
                           ushort* __restrict__ gus_bf,
                           ushort* __restrict__ wdown_bf,
                           ushort* __restrict__ wfuse_bf,
                           ushort* __restrict__ resd,
                           ushort* __restrict__ Apk_g,
                           ushort* __restrict__ Acomb,
                           float* __restrict__ diagsum) {
  int bid = blockIdx.x, tid = threadIdx.x;
  if (bid < 2048) {
    int i = bid * 1024 + tid * 4;
    if (i < 1048576) {
      // gus: permute columns n -> packed r while converting to bf16
      float4 v = *(const float4*)&gus[i];
      int m = i >> 10, n = i & 1023;
      int y = n >> 5, x = n & 31;            // x % 4 == 0
      int idxb = ((y >> 1) << 4) + (x >> 1); // slots idxb, idxb+1 per class
      int py = y & 1;
      ushort2 e0 = {f2bf(v.x), f2bf(v.z)};   // x, x+2  -> even-x class
      ushort2 e1 = {f2bf(v.y), f2bf(v.w)};   // x+1,x+3 -> odd-x class
      *(ushort2*)&gus_bf[(size_t)m * 1024 + (py * 2 + 0) * 256 + idxb] = e0;
      *(ushort2*)&gus_bf[(size_t)m * 1024 + (py * 2 + 1) * 256 + idxb] = e1;
    } else {
      const float* src; ushort* dst; int off;
      if (i < 1572864) { src = wdown; dst = wdown_bf; off = i - 1048576; }
      else { src = wfuse; dst = wfuse_bf; off = i - 1572864; }
      float4 v = *(const float4*)&src[off];
      ushort4 o = {f2bf(v.x), f2bf(v.y), f2bf(v.z), f2bf(v.w)};
      *(ushort4*)&dst[off] = o;
    }
  } else if (bid < 2304) {
    int t8 = (bid - 2048) * 256 + tid;
    uint4 z = {0u, 0u, 0u, 0u};
#pragma unroll
    for (int k = 0; k < 4; ++k) *(uint4*)&resd[(size_t)(t8 + k * 65536) * 8] = z;
  } else if (bid < 5056) {
    int i2 = (bid - 2304) * 256 + tid;  // 0..704511
    int g = i2 / 22016;
    int r = i2 - g * 22016;
    int p = r >> 9;
    int r5 = r & 511;
    int quad = r5 >> 7, m16 = (r5 >> 3) & 15, j = r & 7;
    int k = quad * 8 + j, tp = k >> 4, ic = k & 15;
    float val = 0.f;
    if (p < 25) {
      int t = 2 * p + tp;
      if (t < 49) val = w7[(size_t)(g * 16 + m16) * 784 + ic * 49 + t];
    } else if (p < 38) {
      int t = 2 * (p - 25) + tp;
      if (t < 25) val = w5[(size_t)(g * 16 + m16) * 400 + ic * 25 + t];
    } else {
      int t = 2 * (p - 38) + tp;
      if (t < 9) val = w3[(size_t)(g * 16 + m16) * 144 + ic * 9 + t];
    }
    Apk_g[i2] = f2bf(val);
  } else if (bid < 5568) {
    // zero Acomb (invalid border taps must read as 0)
    int j = (bid - 5056) * 256 + tid;  // < 131072
    uint4 z = {0u, 0u, 0u, 0u};
    ((uint4*)Acomb)[j] = z;
  } else {
    diagsum[tid] = 0.f;
  }
}

// ---------------- SKConv via MFMA: grouped conv as 16x1024xK GEMM -----------
// grid 256 = 32 groups x 8 row-slices; output bf16. 1 block/CU -> fully
// unrolled p-loops so loads batch ahead of the MFMA chain (ILP at 1 wave/SIMD).
__global__ __launch_bounds__(256) void sk_mfma(const float* __restrict__ x,
                                               const ushort* __restrict__ Apk_g,
                                               ushort* __restrict__ feasRawH) {
  __shared__ ushort xg[10 * 38 * 24];  // [lr][cx][ic pad24] bf16, 18.2 KB
  int bid = blockIdx.x, tid = threadIdx.x;
  int g = bid >> 3, sl = bid & 7, y0 = sl * 4;
  for (int i = tid; i < 4560; i += 256) ((uint*)xg)[i] = 0u;
  __syncthreads();
  for (int i = tid; i < 5120; i += 256) {
    int lr = i >> 9, ic = (i >> 5) & 15, xc = i & 31;
    int y = y0 + lr - 3;
    if ((unsigned)y < 32u)
      xg[(lr * 38 + xc + 3) * 24 + ic] =
          f2bf(x[(size_t)(g * 16 + ic) * 1024 + y * 32 + xc]);
  }
  __syncthreads();
  int wv = tid >> 6, lane = tid & 63, quad = lane >> 4, m16 = lane & 15;
  int qh = (quad & 1) * 8, tp = quad >> 1;
  const ushort* Ag = Apk_g + (size_t)g * 22016;
  f32x4 acc[2][3] = {};
#pragma unroll
  for (int p = 0; p < 25; ++p) {  // k7 (br 2)
    bf16x8 af = *(const bf16x8*)&Ag[(p * 4 + quad) * 128 + m16 * 8];
    int t = 2 * p + tp;
    if (t > 48) t = 48;
    int ky = t / 7, kx = t - ky * 7;
#pragma unroll
    for (int ti = 0; ti < 2; ++ti) {
      int T = wv + ti * 4, tl = T >> 1, x0c = (T & 1) * 16;
      bf16x8 bf = *(const bf16x8*)&xg[((tl + ky) * 38 + x0c + m16 + kx) * 24 + qh];
      acc[ti][2] = __builtin_amdgcn_mfma_f32_16x16x32_bf16(af, bf, acc[ti][2], 0, 0, 0);
    }
  }
#pragma unroll
  for (int p = 0; p < 13; ++p) {  // k5 (br 1)
    bf16x8 af = *(const bf16x8*)&Ag[((p + 25) * 4 + quad) * 128 + m16 * 8];
    int t = 2 * p + tp;
    if (t > 24) t = 24;
    int ky = t / 5, kx = t - ky * 5;
#pragma unroll
    for (int ti = 0; ti < 2; ++ti) {
      int T = wv + ti * 4, tl = T >> 1, x0c = (T & 1) * 16;
      bf16x8 bf =
          *(const bf16x8*)&xg[((tl + ky + 1) * 38 + x0c + m16 + kx + 1) * 24 + qh];
      acc[ti][1] = __builtin_amdgcn_mfma_f32_16x16x32_bf16(af, bf, acc[ti][1], 0, 0, 0);
    }
  }
#pragma unroll
  for (int p = 0; p < 5; ++p) {  // k3 (br 0)
    bf16x8 af = *(const bf16x8*)&Ag[((p + 38) * 4 + quad) * 128 + m16 * 8];
    int t = 2 * p + tp;
    if (t > 8) t = 8;
    int ky = t / 3, kx = t - ky * 3;
#pragma unroll
    for (int ti = 0; ti < 2; ++ti) {
      int T = wv + ti * 4, tl = T >> 1, x0c = (T & 1) * 16;
      bf16x8 bf =
          *(const bf16x8*)&xg[((tl + ky + 2) * 38 + x0c + m16 + kx + 2) * 24 + qh];
      acc[ti][0] = __builtin_amdgcn_mfma_f32_16x16x32_bf16(af, bf, acc[ti][0], 0, 0, 0);
    }
  }
  int cb = g * 16 + quad * 4;
#pragma unroll
  for (int ti = 0; ti < 2; ++ti) {
    int T = wv + ti * 4, tl = T >> 1, x0c = (T & 1) * 16;
    int pos = (y0 + tl) * 32 + x0c + m16;
#pragma unroll
    for (int br = 0; br < 3; ++br)
#pragma unroll
      for (int r = 0; r < 4; ++r)
        feasRawH[(size_t)(br * 512 + cb + r) * 1024 + pos] = f2bf(acc[ti][br][r]);
  }
}

// ---------------- InstanceNorm + ReLU + branch-mean (bf16 in/out) -----------
__global__ __launch_bounds__(256) void sk_norm(const ushort* __restrict__ rawH,
                                               ushort* __restrict__ feasH,
                                               float* __restrict__ bmean) {
  __shared__ float red[8];
  int mc = blockIdx.x, tid = threadIdx.x;
  float v[4];
  {
    ushort4 h = *(const ushort4*)&rawH[(size_t)mc * 1024 + tid * 4];
    v[0] = bf2f(h.x); v[1] = bf2f(h.y); v[2] = bf2f(h.z); v[3] = bf2f(h.w);
  }
  float s = 0.f, ss = 0.f;
#pragma unroll
  for (int r = 0; r < 4; ++r) { s += v[r]; ss += v[r] * v[r]; }
  breduce2(s, ss, red);
  float mean = s * (1.f / 1024.f);
  float var = ss * (1.f / 1024.f) - mean * mean;
  float inv = rsqrtf(var + EPSN);
  float rs = 0.f;
  ushort4 o;
#pragma unroll
  for (int r = 0; r < 4; ++r) {
    float t = (v[r] - mean) * inv;
    t = t > 0.f ? t : 0.f;
    ((ushort*)&o)[r] = f2bf(t);
    rs += t;
  }
  *(ushort4*)&feasH[(size_t)mc * 1024 + tid * 4] = o;
  float tot = breduce_sum(rs, red);
  if (tid == 0) bmean[mc] = tot * (1.f / 1024.f);
}

// ---------------- blend + FC-attention; reads bf16 feas ---------------------
__global__ __launch_bounds__(256) void blend_fc(
    const ushort* __restrict__ feasH, const float* __restrict__ bmean,
    const float* __restrict__ wfc, const float* __restrict__ bfc,
    const float* __restrict__ w0, const float* __restrict__ b0,
    const float* __restrict__ w1, const float* __restrict__ b1,
    const float* __restrict__ w2, const float* __restrict__ b2,
    float* __restrict__ res, ushort* __restrict__ Zt2,
    ushort* __restrict__ resd) {
  __shared__ float sfea[512];
  __shared__ float zpart[8][32];
  __shared__ float zz[32];
  __shared__ float lv[3][32];
  __shared__ float attb[3][32];
  __shared__ float tile[32][33];
  int tid = threadIdx.x;
  int pb = blockIdx.x * 32, cb = blockIdx.y * 32;
  for (int c = tid; c < 512; c += 256)
    sfea[c] = bmean[c] + bmean[512 + c] + bmean[1024 + c];
  __syncthreads();
  {
    int j = tid & 31, seg = tid >> 5;
    float p = 0.f;
    for (int c = seg * 64; c < seg * 64 + 64; ++c) p += sfea[c] * wfc[j * 512 + c];
    zpart[seg][j] = p;
  }
  __syncthreads();
  if (tid < 32) {
    float d = bfc[tid];
#pragma unroll
    for (int s = 0; s < 8; ++s) d += zpart[s][tid];
    zz[tid] = d;
  }
  __syncthreads();
  if (tid < 96) {
    int m = tid >> 5, cl = tid & 31;
    const float* wm = (m == 0) ? w0 : (m == 1) ? w1 : w2;
    const float* bm = (m == 0) ? b0 : (m == 1) ? b1 : b2;
    float l = bm[cb + cl];
#pragma unroll
    for (int j = 0; j < 32; ++j) l += zz[j] * wm[(cb + cl) * 32 + j];
    lv[m][cl] = l;
  }
  __syncthreads();
  if (tid < 32) {
    float l0 = lv[0][tid], l1 = lv[1][tid], l2 = lv[2][tid];
    float mx = fmaxf(l0, fmaxf(l1, l2));
    float e0 = expf(l0 - mx), e1 = expf(l1 - mx), e2 = expf(l2 - mx);
    float inv = 1.f / (e0 + e1 + e2);
    attb[0][tid] = e0 * inv; attb[1][tid] = e1 * inv; attb[2][tid] = e2 * inv;
  }
  __syncthreads();
  int tx = tid & 31, ty = tid >> 5;
  int pos = pb + tx;
  int yy = pos >> 5, xx = pos & 31;
  int ki0 = (yy + 1) & 1, pi0 = (yy + 1 - ki0) >> 1;
  int kj0 = (xx + 1) & 1, pj0 = (xx + 1 - kj0) >> 1;
#pragma unroll
  for (int r = 0; r < 4; ++r) {
    int cl = ty + r * 8;
    int c = cb + cl;
    float v = bf2f(feasH[(size_t)c * 1024 + pos]) * attb[0][cl] +
              bf2f(feasH[(size_t)(512 + c) * 1024 + pos]) * attb[1][cl] +
              bf2f(feasH[(size_t)(1024 + c) * 1024 + pos]) * attb[2][cl];
    res[c * 1024 + pos] = v;
    tile[cl][tx] = v;
    ushort bv16 = f2bf(v);
#pragma unroll
    for (int ai = 0; ai < 2; ++ai) {
      int ki = ki0 + 2 * ai, pi = pi0 - ai;
      if ((unsigned)pi >= 16u) continue;
#pragma unroll
      for (int aj = 0; aj < 2; ++aj) {
        int kj = kj0 + 2 * aj, pj = pj0 - aj;
        if ((unsigned)pj >= 16u) continue;
        resd[((size_t)(ki * 4 + kj) << 17) + (size_t)c * 256 + pi * 16 + pj] = bv16;
      }
    }
  }
  __syncthreads();
#pragma unroll
  for (int r = 0; r < 4; ++r) {
    int pl = ty + r * 8;
    Zt2[(size_t)(pb + pl) * 1024 + 512 + cb + tx] = f2bf(tile[tx][pl]);
  }
}

// ---------------- Gram split-K partials, SYMMETRIC (upper pairs only) -------
// grid (10,1,32): 10 upper-triangle 64x64 tile-pairs x 32 K-chunks.
// Off-diagonal pairs store both the tile and its transpose; diagonal pairs
// also accumulate the Gram diagonal into diagsum via atomics.
__global__ __launch_bounds__(256) void gram_part2(const float* __restrict__ res,
                                                  float* __restrict__ Apart,
                                                  float* __restrict__ diagsum) {
  __shared__ float ch[4][324];
  const int PBT[10] = {0, 0, 0, 0, 1, 1, 1, 2, 2, 3};
  const int QBT[10] = {0, 1, 2, 3, 1, 2, 3, 2, 3, 3};
  int tid = threadIdx.x;
  int pid = blockIdx.x;
  int pb = PBT[pid] * 64, qb = QBT[pid] * 64;
  int kc = blockIdx.z;
  int tx = tid & 15, ty = tid >> 4;
  for (int i = tid; i < 4 * 324; i += 256) ((float*)ch)[i] = 0.f;
  int pi = (pb + ty * 4) >> 4, pj = (pb + ty * 4) & 15;
  int qi = (qb + tx * 4) >> 4, qj = (qb + tx * 4) & 15;
  int lane = tid & 63, wv = tid >> 6;
  int sr = lane >> 2, sc = (lane & 3) * 4;
  float acc[4][4] = {};
  for (int c0 = kc * 16; c0 < kc * 16 + 16; c0 += 4) {
    __syncthreads();
    {
      const float* src = res + (size_t)(c0 + wv) * 1024 + (2 * sr) * 32 + 2 * sc;
      float4 r0a = *(const float4*)src;
      float4 r0b = *(const float4*)(src + 4);
      float4 r1a = *(const float4*)(src + 32);
      float4 r1b = *(const float4*)(src + 36);
      float* dst = &ch[wv][(sr + 1) * 18 + sc + 1];
      dst[0] = 0.25f * (r0a.x + r0a.y + r1a.x + r1a.y);
      dst[1] = 0.25f * (r0a.z + r0a.w + r1a.z + r1a.w);
      dst[2] = 0.25f * (r0b.x + r0b.y + r1b.x + r1b.y);
      dst[3] = 0.25f * (r0b.z + r0b.w + r1b.z + r1b.w);
    }
    __syncthreads();
#pragma unroll
    for (int cc = 0; cc < 4; ++cc) {
      float ps[3][6], qs[3][6];
#pragma unroll
      for (int u = 0; u < 3; ++u) {
        const float* pr = &ch[cc][(pi + u) * 18 + pj];
        const float* qr = &ch[cc][(qi + u) * 18 + qj];
#pragma unroll
        for (int t = 0; t < 6; ++t) { ps[u][t] = pr[t]; qs[u][t] = qr[t]; }
      }
#pragma unroll
      for (int u = 0; u < 3; ++u)
#pragma unroll
        for (int v = 0; v < 3; ++v)
#pragma unroll
          for (int i = 0; i < 4; ++i)
#pragma unroll
            for (int j = 0; j < 4; ++j)
              acc[i][j] += ps[u][v + i] * qs[u][v + j];
    }
  }
#pragma unroll
  for (int i = 0; i < 4; ++i) {
    float4 o4 = {acc[i][0], acc[i][1], acc[i][2], acc[i][3]};
    *(float4*)&Apart[(size_t)kc * 65536 + (pb + ty * 4 + i) * 256 + qb + tx * 4] = o4;
  }
  if (pb != qb) {
    // mirror tile: element (row,col) -> (col,row); columns of acc are
    // contiguous in the transposed tile -> float4 stores.
#pragma unroll
    for (int j = 0; j < 4; ++j) {
      float4 o4 = {acc[0][j], acc[1][j], acc[2][j], acc[3][j]};
      *(float4*)&Apart[(size_t)kc * 65536 + (qb + tx * 4 + j) * 256 + pb + ty * 4] = o4;
    }
  } else if (tx == ty) {
#pragma unroll
    for (int i = 0; i < 4; ++i) atomicAdd(&diagsum[pb + tx * 4 + i], acc[i][i]);
  }
}

// ---------------- softmax + diag norm -> Acomb (class-packed rows) ----------
__global__ __launch_bounds__(256) void attn_soft4(const float* __restrict__ Apart,
                                                  const float* __restrict__ diagsum,
                                                  ushort* __restrict__ Acomb) {
  __shared__ float red[8];
  int q = blockIdx.x, t = threadIdx.x;
  float d = diagsum[t];
  float s = 0.f;
#pragma unroll
  for (int k = 0; k < 32; ++k) s += Apart[(size_t)k * 65536 + q * 256 + t];
  float invn = 10.f / fmaxf(sqrtf(fmaxf(d, 0.f)), 1e-4f);
  float v = s * invn;
  float mx = breduce_max(v, red);
  float e = expf(v - mx);
  float sm = breduce_sum(e, red);
  ushort val = f2bf(e / sm);
  int qi = q >> 4, qj = q & 15;
#pragma unroll
  for (int ki = 0; ki < 4; ++ki) {
    int y = 2 * qi + ki - 1;
    if ((unsigned)y >= 32u) continue;
#pragma unroll
    for (int kj = 0; kj < 4; ++kj) {
      int x = 2 * qj + kj - 1;
      if ((unsigned)x >= 32u) continue;
      int cls = (y & 1) * 2 + (x & 1);
      int idx = ((y >> 1) << 4) + (x >> 1);
      int seg = ((ki >> 1) << 1) + (kj >> 1);
      Acomb[(size_t)(cls * 256 + idx) * 1024 + seg * 256 + t] = val;
    }
  }
}

// ---------------- fused tconv+tcomb: K=4x256 GEMM over class-shared taps ----
__global__ __launch_bounds__(256) void tconv2(const ushort* __restrict__ Acomb,
                                              const ushort* __restrict__ resd,
                                              float* __restrict__ orlt,
                                              float* __restrict__ sigt,
                                              ushort* __restrict__ orlT) {
  __shared__ float tl[64][33];
  int tid = threadIdx.x;
  int wv = tid >> 6, lane = tid & 63, quad = lane >> 4, m16 = lane & 15;
  int nb = blockIdx.x * 32;   // channel tile (16 blocks x 32 = 512)
  int mb = blockIdx.y * 64;   // packed-row tile (16 blocks x 64 = 1024)
  int cls = blockIdx.y >> 2;  // 4 row-blocks per parity class
  int py = cls >> 1, px = cls & 1;
  int row0 = mb + wv * 16 + m16;
  const ushort* Ap = Acomb + (size_t)row0 * 1024 + quad * 8;
  f32x4 ac0 = {0.f, 0.f, 0.f, 0.f}, ac1 = ac0;
#pragma unroll
  for (int sg = 0; sg < 4; ++sg) {
    int ki = 2 * (sg >> 1) + 1 - py;
    int kj = 2 * (sg & 1) + 1 - px;
    const ushort* Bp =
        resd + ((size_t)(ki * 4 + kj) << 17) + (size_t)(nb + m16) * 256 + quad * 8;
    const ushort* As = Ap + sg * 256;
#pragma unroll 4
    for (int k0 = 0; k0 < 256; k0 += 32) {
      bf16x8 af = *(const bf16x8*)(As + k0);
      bf16x8 b0 = *(const bf16x8*)(Bp + k0);
      bf16x8 b1 = *(const bf16x8*)(Bp + 16 * 256 + k0);
      ac0 = __builtin_amdgcn_mfma_f32_16x16x32_bf16(af, b0, ac0, 0, 0, 0);
      ac1 = __builtin_amdgcn_mfma_f32_16x16x32_bf16(af, b1, ac1, 0, 0, 0);
    }
  }
  int rloc0 = wv * 16 + quad * 4;
  f32x4 accs[2] = {ac0, ac1};
#pragma unroll
  for (int nt = 0; nt < 2; ++nt) {
    int c = nb + nt * 16 + m16;
#pragma unroll
    for (int r = 0; r < 4; ++r) {
      int rl = rloc0 + r;
      int idx = (mb + rl) & 255;
      int y = ((idx >> 4) << 1) + py;
      int x = ((idx & 15) << 1) + px;
      int n = y * 32 + x;
      float v = accs[nt][r] * 0.25f;
      orlt[n * 512 + c] = v;
      sigt[n * 512 + c] = 1.f / (1.f + expf(-v));
      tl[rl][nt * 16 + m16] = v;
    }
  }
  __syncthreads();
  int r_l = tid & 63;
#pragma unroll
  for (int k = 0; k < 8; ++k) {
    int c_l = (tid >> 6) + k * 4;
    orlT[(size_t)(nb + c_l) * 1024 + mb + r_l] = f2bf(tl[r_l][c_l]);
  }
}

// ---------------- merged: gus GEMM (blocks 0..127) + CSA (128..1151) --------
__global__ __launch_bounds__(256) void gus_csa(
    const ushort* __restrict__ gus_bf, const ushort* __restrict__ orlT,
    const float* __restrict__ sigt, const float* __restrict__ orlt,
    ushort* __restrict__ Zt) {
  __shared__ float red9[4][9];
  __shared__ float a9s[9];
  int tid = threadIdx.x;
  if (blockIdx.x < 128) {
    const int K = 1024;
    int wv = tid >> 6, lane = tid & 63;
    int quad = lane >> 4, m16 = lane & 15;
    int nb = (blockIdx.x & 7) * 64, mb = (blockIdx.x >> 3) * 64;
    const ushort* Ap = gus_bf + (size_t)(mb + wv * 16 + m16) * K + quad * 8;
    const ushort* Bp = orlT + (size_t)(nb + m16) * K + quad * 8;
    f32x4 ac0 = {0.f, 0.f, 0.f, 0.f}, ac1 = ac0, ac2 = ac0, ac3 = ac0;
#pragma unroll 4
    for (int k0 = 0; k0 < K; k0 += 32) {
      bf16x8 af = *(const bf16x8*)(Ap + k0);
      bf16x8 b0 = *(const bf16x8*)(Bp + k0);
      bf16x8 b1 = *(const bf16x8*)(Bp + (size_t)16 * K + k0);
      bf16x8 b2 = *(const bf16x8*)(Bp + (size_t)32 * K + k0);
      bf16x8 b3 = *(const bf16x8*)(Bp + (size_t)48 * K + k0);
      ac0 = __builtin_amdgcn_mfma_f32_16x16x32_bf16(af, b0, ac0, 0, 0, 0);
      ac1 = __builtin_amdgcn_mfma_f32_16x16x32_bf16(af, b1, ac1, 0, 0, 0);
      ac2 = __builtin_amdgcn_mfma_f32_16x16x32_bf16(af, b2, ac2, 0, 0, 0);
      ac3 = __builtin_amdgcn_mfma_f32_16x16x32_bf16(af, b3, ac3, 0, 0, 0);
    }
    int row = mb + wv * 16 + quad * 4;
    f32x4 accs[4] = {ac0, ac1, ac2, ac3};
#pragma unroll
    for (int nt = 0; nt < 4; ++nt) {
      int c = nb + nt * 16 + m16;
#pragma unroll
      for (int r = 0; r < 4; ++r) {
        int p = row + r;
        int pos = ((p & 1) << 9) + c;
        int kk = p >> 1;
        Zt[(size_t)pos * 1024 + kk] = f2bf(accs[nt][r]);
      }
    }
    return;
  }
  int n = blockIdx.x - 128;
  int ny = n >> 5, nx = n & 31;
  int c2 = tid * 2;
  int lane = tid & 63, wid = tid >> 6;
  float2 ctr = *(const float2*)&sigt[n * 512 + c2];
  float part[9];
#pragma unroll
  for (int u = 0; u < 3; ++u) {
    int yy = ny + u - 1;
#pragma unroll
    for (int v = 0; v < 3; ++v) {
      int xx = nx + v - 1;
      float2 nb2 = {0.f, 0.f};
      if ((unsigned)yy < 32u && (unsigned)xx < 32u)
        nb2 = *(const float2*)&sigt[(yy * 32 + xx) * 512 + c2];
      part[u * 3 + v] = ctr.x * nb2.x + ctr.y * nb2.y;
    }
  }
  // batched 9-way reduction: one LDS round instead of nine
#pragma unroll
  for (int t = 0; t < 9; ++t)
#pragma unroll
    for (int o = 32; o > 0; o >>= 1) part[t] += __shfl_down(part[t], o);
  if (lane == 0)
#pragma unroll
    for (int t = 0; t < 9; ++t) red9[wid][t] = part[t];
  __syncthreads();
  if (tid == 0) {
    float a[9];
#pragma unroll
    for (int t = 0; t < 9; ++t)
      a[t] = (red9[0][t] + red9[1][t] + red9[2][t] + red9[3][t]) * (1.f / 512.f);
    float mx = a[0];
#pragma unroll
    for (int t = 1; t < 9; ++t) mx = fmaxf(mx, a[t]);
    float sum = 0.f;
#pragma unroll
    for (int t = 0; t < 9; ++t) { a[t] = expf(a[t] - mx); sum += a[t]; }
    float inv = 1.f / sum;
#pragma unroll
    for (int t = 0; t < 9; ++t) a9s[t] = a[t] * inv;
  }
  __syncthreads();
  float2 acc = {0.f, 0.f};
#pragma unroll
  for (int u = 0; u < 3; ++u) {
    int yy = ny + u - 1;
#pragma unroll
    for (int v = 0; v < 3; ++v) {
      int xx = nx + v - 1;
      if ((unsigned)yy < 32u && (unsigned)xx < 32u) {
        float w = a9s[u * 3 + v];
        float2 ov = *(const float2*)&orlt[(yy * 32 + xx) * 512 + c2];
        acc.x += w * ov.x;
        acc.y += w * ov.y;
      }
    }
  }
  int kk = 512 + (n >> 1);
  int pos0 = ((n & 1) << 9) + c2;
  Zt[(size_t)pos0 * 1024 + kk] = f2bf(acc.x);
  Zt[(size_t)(pos0 + 1) * 1024 + kk] = f2bf(acc.y);
}

// ---------------- K-split bf16 MFMA GEMM: 2 halves -> 2 fp32 partials -------
__global__ __launch_bounds__(256) void mfma_gemm_ks(const ushort* __restrict__ A,
                                                    const ushort* __restrict__ Bt,
                                                    float* __restrict__ Cp,
                                                    int N) {
  const int KF = 1024;
  int tid = threadIdx.x;
  int wv = tid >> 6, lane = tid & 63;
  int quad = lane >> 4, m16 = lane & 15;
  int nb = blockIdx.x * 64, mb = blockIdx.y * 64;
  int kh = blockIdx.z;
  const ushort* Ap = A + (size_t)(mb + wv * 16 + m16) * KF + kh * 512 + quad * 8;
  const ushort* Bp = Bt + (size_t)(nb + m16) * KF + kh * 512 + quad * 8;
  f32x4 ac0 = {0.f, 0.f, 0.f, 0.f}, ac1 = ac0, ac2 = ac0, ac3 = ac0;
#pragma unroll 4
  for (int k0 = 0; k0 < 512; k0 += 32) {
    bf16x8 af = *(const bf16x8*)(Ap + k0);
    bf16x8 b0 = *(const bf16x8*)(Bp + k0);
    bf16x8 b1 = *(const bf16x8*)(Bp + (size_t)16 * KF + k0);
    bf16x8 b2 = *(const bf16x8*)(Bp + (size_t)32 * KF + k0);
    bf16x8 b3 = *(const bf16x8*)(Bp + (size_t)48 * KF + k0);
    ac0 = __builtin_amdgcn_mfma_f32_16x16x32_bf16(af, b0, ac0, 0, 0, 0);
    ac1 = __builtin_amdgcn_mfma_f32_16x16x32_bf16(af, b1, ac1, 0, 0, 0);
    ac2 = __builtin_amdgcn_mfma_f32_16x16x32_bf16(af, b2, ac2, 0, 0, 0);
    ac3 = __builtin_amdgcn_mfma_f32_16x16x32_bf16(af, b3, ac3, 0, 0, 0);
  }
  int row = mb + wv * 16 + quad * 4;
  float* C = Cp + (size_t)kh * 524288;
  f32x4 accs[4] = {ac0, ac1, ac2, ac3};
#pragma unroll
  for (int nt = 0; nt < 4; ++nt)
#pragma unroll
    for (int r = 0; r < 4; ++r)
      C[(size_t)(row + r) * N + nb + nt * 16 + m16] = accs[nt][r];
}

// ---------------- InstanceNorm + LeakyReLU (sum 2 partials) -> Zt2 bf16 -----
__global__ __launch_bounds__(256) void norm_down2(const float* __restrict__ ra,
                                                  ushort* __restrict__ Zt2) {
  __shared__ float red[8];
  int c = blockIdx.x, tid = threadIdx.x;
  float v[4];
  float s = 0.f, ss = 0.f;
#pragma unroll
  for (int r = 0; r < 4; ++r) {
    int i = c * 1024 + tid + r * 256;
    v[r] = ra[i] + ra[524288 + i];
    s += v[r];
    ss += v[r] * v[r];
  }
  breduce2(s, ss, red);
  float mean = s * (1.f / 1024.f);
  float var = ss * (1.f / 1024.f) - mean * mean;
  float inv = rsqrtf(var + EPSN);
#pragma unroll
  for (int r = 0; r < 4; ++r) {
    float t = (v[r] - mean) * inv;
    t = t >= 0.f ? t : 0.2f * t;
    Zt2[(size_t)(tid + r * 256) * 1024 + c] = f2bf(t);
  }
}

// ---------------- final InstanceNorm + LeakyReLU (sum 2 partials) -----------
__global__ __launch_bounds__(256) void norm_leaky2(const float* __restrict__ ra,
                                                   float* __restrict__ out) {
  __shared__ float red[8];
  int c = blockIdx.x, tid = threadIdx.x;
  float v[4];
  float s = 0.f, ss = 0.f;
#pragma unroll
  for (int r = 0; r < 4; ++r) {
    int i = c * 1024 + tid + r * 256;
    v[r] = ra[i] + ra[524288 + i];
    s += v[r];
    ss += v[r] * v[r];
  }
  breduce2(s, ss, red);
  float mean = s * (1.f / 1024.f);
  float var = ss * (1.f / 1024.f) - mean * mean;
  float inv = rsqrtf(var + EPSN);
#pragma unroll
  for (int r = 0; r < 4; ++r) {
    float t = (v[r] - mean) * inv;
    out[c * 1024 + tid + r * 256] = t >= 0.f ? t : 0.2f * t;
  }
}

// ---------------- host launch ------------------------------------------------
extern "C" void kernel_launch(void* const* d_in, const int* in_sizes, int n_in,
                              void* d_out, int out_size, void* d_ws, size_t ws_size,
                              hipStream_t stream) {
  const float* x = (const float*)d_in[0];
  const float* gus = (const float*)d_in[1];
  const float* w3 = (const float*)d_in[2];
  const float* w5 = (const float*)d_in[4];
  const float* w7 = (const float*)d_in[6];
  const float* wfc = (const float*)d_in[8];
  const float* bfc = (const float*)d_in[9];
  const float* w0 = (const float*)d_in[10];
  const float* b0 = (const float*)d_in[11];
  const float* w1 = (const float*)d_in[12];
  const float* b1 = (const float*)d_in[13];
  const float* w2 = (const float*)d_in[14];
  const float* b2 = (const float*)d_in[15];
  const float* wdown = (const float*)d_in[16];
  const float* wfuse = (const float*)d_in[17];

  float* ws = (float*)d_ws;
  ushort* feasH = (ushort*)ws;           // 1572864 ush (dead after blend_fc)
  float* rawP = ws + 786432;             // 2x524288 fl partials (written late)
  ushort* Acomb = (ushort*)rawP;         // 1048576 ush; dead before rawP written
  float* bmean = ws + 1835008;           // 1536
  float* res = bmean + 1536;             // 524288
  float* Zt2f = res + 524288;            // 524288 fl
  ushort* Zt2 = (ushort*)Zt2f;
  float* T = Zt2f + 524288;              // 2097152 (alias region)
  ushort* feasRawH = (ushort*)T;         // 1572864 ush (dead before gram)
  float* Apart = T;                      // 32x65536 fl (dead before Zt written)
  ushort* Zt = (ushort*)T;               // (written by gus_csa)
  float* orlt = T + 2097152;             // 524288
  float* sigt = orlt + 524288;           // 524288
  ushort* orlT = (ushort*)(sigt + 524288);        // 262144 fl
  ushort* gus_bf = (ushort*)(sigt + 819200);      // 524288 fl
  ushort* wdown_bf = (ushort*)(sigt + 1343488);   // 262144 fl
  ushort* wfuse_bf = (ushort*)(sigt + 1605632);   // 262144 fl
  ushort* resd = (ushort*)(sigt + 1867776);       // 1048576 fl
  ushort* Apk_g = (ushort*)(sigt + 2916352);      // 704512 ush = 352256 fl
  float* diagsum = sigt + 3268608;                // 256 fl

  pre_kernel<<<5569, 256, 0, stream>>>(gus, wdown, wfuse, w3, w5, w7, gus_bf,
                                       wdown_bf, wfuse_bf, resd, Apk_g, Acomb,
                                       diagsum);
  sk_mfma<<<256, 256, 0, stream>>>(x, Apk_g, feasRawH);
  sk_norm<<<1536, 256, 0, stream>>>(feasRawH, feasH, bmean);
  blend_fc<<<dim3(32, 16), 256, 0, stream>>>(feasH, bmean, wfc, bfc, w0, b0, w1,
                                             b1, w2, b2, res, Zt2, resd);
  gram_part2<<<dim3(10, 1, 32), 256, 0, stream>>>(res, Apart, diagsum);
  attn_soft4<<<256, 256, 0, stream>>>(Apart, diagsum, Acomb);
  tconv2<<<dim3(16, 16), 256, 0, stream>>>(Acomb, resd, orlt, sigt, orlT);
  gus_csa<<<1152, 256, 0, stream>>>(gus_bf, orlT, sigt, orlt, Zt);
  mfma_gemm_ks<<<dim3(16, 8, 2), 256, 0, stream>>>(wdown_bf, Zt, rawP, 1024);
  norm_down2<<<512, 256, 0, stream>>>(rawP, Zt2);
  mfma_gemm_ks<<<dim3(16, 8, 2), 256, 0, stream>>>(wfuse_bf, Zt2, rawP, 1024);
  norm_leaky2<<<512, 256, 0, stream>>>(rawP, (float*)d_out);
}